// Round 1
// 1150.634 us; speedup vs baseline: 1.1172x; 1.1172x over previous
//
#include <hip/hip_runtime.h>

#define N_ 768
#define CS 384
#define CZ 128
#define HH 12
#define PQ_ 4
#define PV_ 8

// ---------------------------------------------------------------------------
// K0: zb[n][m][12] = sqrt(1/3) * (z[n,m,:] @ w_b[h,:] + b_b[h])
// Massively parallel, coalesced z read (this is the single full-HBM pass).
// grid = 768 n * 12 m-tiles of 64, block = 256.
// ---------------------------------------------------------------------------
__global__ __launch_bounds__(256, 4) void k_zb(
    const float* __restrict__ z,
    const float* __restrict__ w_b, const float* __restrict__ b_b,
    float* __restrict__ zb)
{
    const int bid = blockIdx.x;
    const int n  = bid / 12;
    const int m0 = (bid % 12) * 64;
    const int tid = threadIdx.x;

    __shared__ float zs[64 * 133];   // 64 rows x 128, stride 133 (odd: no bank conflict)
    __shared__ float zbt[64 * 12];   // staged output tile

    // coalesced load of z[n, m0:m0+64, 0:128]
    const float4* zsrc = (const float4*)(z + ((size_t)n * N_ + m0) * CZ);
    #pragma unroll
    for (int j = 0; j < 8; ++j) {
        int idx = tid + j * 256;            // 2048 float4s
        float4 zv = zsrc[idx];
        int f  = idx << 2;
        int ml = f >> 7;
        int c  = f & 127;
        float* d = &zs[ml * 133 + c];
        d[0] = zv.x; d[1] = zv.y; d[2] = zv.z; d[3] = zv.w;
    }
    __syncthreads();

    // thread = (m-row, head-quarter): 3 heads per thread
    const int ml = tid & 63;
    const int hq = __builtin_amdgcn_readfirstlane(tid >> 6);  // wave-uniform -> s_loads
    const float* w0 = w_b + (hq * 3 + 0) * CZ;
    const float* w1 = w0 + CZ;
    const float* w2 = w1 + CZ;
    const float* zrow = &zs[ml * 133];
    float a0 = 0.f, a1 = 0.f, a2 = 0.f;
    #pragma unroll 8
    for (int c = 0; c < CZ; ++c) {
        float zv = zrow[c];
        a0 += zv * w0[c];
        a1 += zv * w1[c];
        a2 += zv * w2[c];
    }
    const float s3 = 0.5773502691896258f;   // sqrt(1/3)
    zbt[ml * 12 + hq * 3 + 0] = s3 * (a0 + b_b[hq * 3 + 0]);
    zbt[ml * 12 + hq * 3 + 1] = s3 * (a1 + b_b[hq * 3 + 1]);
    zbt[ml * 12 + hq * 3 + 2] = s3 * (a2 + b_b[hq * 3 + 2]);
    __syncthreads();

    // coalesced store: 768 contiguous floats = 192 float4
    float4* dst = (float4*)(zb + ((size_t)n * N_ + m0) * 12);
    if (tid < 192) dst[tid] = ((const float4*)zbt)[tid];
}

// ---------------------------------------------------------------------------
// K1: projections per residue n. (all fp32)
// raw[0:192]   = q rows
// raw[192:576] = kv rows (h*32 + c; c<16 -> k, else v)
// raw[576:720] = q_pts proj (coord*48 + hp), hp = h*4+p
// raw[720:1152]= kv_pts proj (coord*144 + j), j = h*12+p (p<4 k_pts else v_pts)
// v and v_pts are written fused into vcat[m][480] = [v(192) | vp(288)]
// ---------------------------------------------------------------------------
__global__ __launch_bounds__(256) void k_proj(
    const float* __restrict__ s,
    const float* __restrict__ rot,
    const float* __restrict__ trans,
    const float* __restrict__ w_q,  const float* __restrict__ b_q,
    const float* __restrict__ w_kv, const float* __restrict__ b_kv,
    const float* __restrict__ w_qp, const float* __restrict__ b_qp,
    const float* __restrict__ w_kvp,const float* __restrict__ b_kvp,
    float* __restrict__ q, float* __restrict__ k,
    float* __restrict__ qp, float* __restrict__ kp,
    float* __restrict__ vcat)
{
    const int n   = blockIdx.x;
    const int tid = threadIdx.x;
    __shared__ float s_sh[CS];
    __shared__ float raw[1152];
    __shared__ float R[9], T[3];

    for (int i = tid; i < CS; i += 256) s_sh[i] = s[n * CS + i];
    if (tid < 9) R[tid] = rot[n * 9 + tid];
    if (tid < 3) T[tid] = trans[n * 3 + tid];
    __syncthreads();

    for (int idx = tid; idx < 1152; idx += 256) {
        const float* wrow;
        float bias;
        if (idx < 192)      { wrow = w_q + idx * CS;               bias = b_q[idx]; }
        else if (idx < 576) { int r = idx - 192; wrow = w_kv + r * CS;  bias = b_kv[r]; }
        else if (idx < 720) { int r = idx - 576; wrow = w_qp + r * CS;  bias = b_qp[r]; }
        else                { int r = idx - 720; wrow = w_kvp + r * CS; bias = b_kvp[r]; }
        float acc = bias;
        const float4* w4 = (const float4*)wrow;
        #pragma unroll 4
        for (int c4 = 0; c4 < CS / 4; ++c4) {
            float4 wv = w4[c4];
            const float* sp = &s_sh[c4 * 4];
            acc += sp[0] * wv.x + sp[1] * wv.y + sp[2] * wv.z + sp[3] * wv.w;
        }
        raw[idx] = acc;
    }
    __syncthreads();

    for (int i = tid; i < 192; i += 256) {
        q[n * 192 + i] = raw[i];
        int h = i >> 4, c = i & 15;
        k[n * 192 + i] = raw[192 + h * 32 + c];
        vcat[n * 480 + i] = raw[192 + h * 32 + 16 + c];
    }
    for (int hp = tid; hp < 48; hp += 256) {
        float x = raw[576 + hp], y = raw[576 + 48 + hp], zc = raw[576 + 96 + hp];
        #pragma unroll
        for (int i = 0; i < 3; ++i)
            qp[n * 144 + hp * 3 + i] = R[i * 3 + 0] * x + R[i * 3 + 1] * y + R[i * 3 + 2] * zc + T[i];
    }
    for (int j = tid; j < 144; j += 256) {
        float x = raw[720 + j], y = raw[720 + 144 + j], zc = raw[720 + 288 + j];
        float p0 = R[0] * x + R[1] * y + R[2] * zc + T[0];
        float p1 = R[3] * x + R[4] * y + R[5] * zc + T[1];
        float p2 = R[6] * x + R[7] * y + R[8] * zc + T[2];
        int h = j / 12, p = j % 12;
        if (p < PQ_) {
            int o = n * 144 + (h * PQ_ + p) * 3;
            kp[o] = p0; kp[o + 1] = p1; kp[o + 2] = p2;
        } else {
            int o = n * 480 + 192 + (h * PV_ + (p - PQ_)) * 3;
            vcat[o] = p0; vcat[o + 1] = p1; vcat[o + 2] = p2;
        }
    }
}

// ---------------------------------------------------------------------------
// K2 (fused): per residue n — logits (bias precomputed in k_zb), softmax in
// LDS, then o+o_pt in one pass over vcat, o_pair = a@z, inv-rot + norms.
// n iterated in REVERSE so the o_pair z re-read walks the LLC-resident tail
// left by k_zb. LDS ~52 KB, launch_bounds(256,3) -> 3 blocks/CU co-resident.
// ---------------------------------------------------------------------------
__global__ __launch_bounds__(256, 3) void k_fused(
    const float* __restrict__ q, const float* __restrict__ k,
    const float* __restrict__ qp, const float* __restrict__ kp,
    const float* __restrict__ vcat,
    const float* __restrict__ zb,
    const float* __restrict__ z,
    const float* __restrict__ head_weights,
    const float* __restrict__ mask,
    const float* __restrict__ rot, const float* __restrict__ trans,
    float* __restrict__ ocat)
{
    const int n   = (N_ - 1) - blockIdx.x;
    const int tid = threadIdx.x;

    __shared__ float qv[192], qpt[144];
    __shared__ float hw[HH];
    __shared__ float L[HH * N_];             // 36 KB: logits -> probs
    __shared__ float og[288];
    __shared__ float part[2 * HH * CZ];      // 12 KB
    __shared__ float R[9], T[3];

    for (int i = tid; i < 192; i += 256) qv[i] = q[n * 192 + i];
    for (int i = tid; i < 144; i += 256) qpt[i] = qp[n * 144 + i];
    if (tid < HH) {
        float x = head_weights[tid];
        // softplus(x) * sqrt(1/(3*(PQ*9/2)))
        hw[tid] = 0.13608276348795434f * logf(1.0f + expf(x));
    }
    if (tid < 9) R[tid] = rot[n * 9 + tid];
    if (tid < 3) T[tid] = trans[n * 3 + tid];
    __syncthreads();

    const float mn = mask[n];

    // ---- pass 1: logits for all (h, m); z bias comes precomputed from zb ----
    for (int m = tid; m < N_; m += 256) {
        const float4* zb4 = (const float4*)(zb + (size_t)(n * N_ + m) * 12);
        float4 zq0 = zb4[0], zq1 = zb4[1], zq2 = zb4[2];
        float zbias[12] = { zq0.x, zq0.y, zq0.z, zq0.w,
                            zq1.x, zq1.y, zq1.z, zq1.w,
                            zq2.x, zq2.y, zq2.z, zq2.w };
        float mterm = (mn * mask[m] - 1.0f) * 100000.0f;
        const float4* kr4 = (const float4*)(k  + m * 192);
        const float*  kpr = kp + m * 144;
        #pragma unroll
        for (int h = 0; h < HH; ++h) {
            float acc = 0.f;
            #pragma unroll
            for (int c4 = 0; c4 < 4; ++c4) {
                float4 kv = kr4[h * 4 + c4];
                const float* qq = &qv[h * 16 + c4 * 4];
                acc += qq[0] * kv.x + qq[1] * kv.y + qq[2] * kv.z + qq[3] * kv.w;
            }
            acc *= 0.14433756729740643f;            // sqrt(1/48)
            acc += zbias[h];
            float d2;
            {
                const float4* kq = (const float4*)(kpr + h * 12);
                float4 a = kq[0], b = kq[1], cc = kq[2];
                const float* qp_ = &qpt[h * 12];
                float dx, dy, dz;
                dx = qp_[0] - a.x;  dy = qp_[1] - a.y;  dz = qp_[2] - a.z;
                d2  = dx * dx + dy * dy + dz * dz;
                dx = qp_[3] - a.w;  dy = qp_[4] - b.x;  dz = qp_[5] - b.y;
                d2 += dx * dx + dy * dy + dz * dz;
                dx = qp_[6] - b.z;  dy = qp_[7] - b.w;  dz = qp_[8] - cc.x;
                d2 += dx * dx + dy * dy + dz * dz;
                dx = qp_[9] - cc.y; dy = qp_[10] - cc.z; dz = qp_[11] - cc.w;
                d2 += dx * dx + dy * dy + dz * dz;
            }
            acc -= 0.5f * hw[h] * d2;
            L[h * N_ + m] = acc + mterm;
        }
    }
    __syncthreads();

    // ---- pass 2: softmax per head; wave w handles heads w, w+4, w+8 ----
    {
        const int wv_ = tid >> 6, lane = tid & 63;
        #pragma unroll
        for (int j = 0; j < 3; ++j) {
            const int h = wv_ + 4 * j;
            float vals[12];
            float mx = -1e30f;
            #pragma unroll
            for (int t = 0; t < 12; ++t) {
                vals[t] = L[h * N_ + lane + 64 * t];
                mx = fmaxf(mx, vals[t]);
            }
            #pragma unroll
            for (int off = 32; off; off >>= 1) mx = fmaxf(mx, __shfl_xor(mx, off));
            float sum = 0.f;
            #pragma unroll
            for (int t = 0; t < 12; ++t) { vals[t] = expf(vals[t] - mx); sum += vals[t]; }
            #pragma unroll
            for (int off = 32; off; off >>= 1) sum += __shfl_xor(sum, off);
            float inv = 1.0f / sum;
            #pragma unroll
            for (int t = 0; t < 12; ++t) L[h * N_ + lane + 64 * t] = vals[t] * inv;
        }
    }
    __syncthreads();

    float* oc = ocat + (size_t)n * 2112;

    // ---- o (192) and o_pt (288) in ONE pass over vcat[m][480]: all 256
    //      threads active, 2 accumulators each ----
    {
        const int i0 = tid;              // 0..255
        const int i1 = tid + 256;        // 256..511 (active < 480)
        const bool act1 = (i1 < 480);
        const int h0 = (i0 < 192) ? (i0 >> 4) : ((i0 - 192) / 24);
        const int h1 = act1 ? ((i1 - 192) / 24) : 0;
        const float* Lh0 = L + h0 * N_;
        const float* Lh1 = L + h1 * N_;
        const float* vc0 = vcat + i0;
        const float* vc1 = vcat + (act1 ? i1 : 0);
        float a0 = 0.f, a1 = 0.f;
        #pragma unroll 4
        for (int m = 0; m < N_; ++m) {
            float x0 = vc0[(size_t)m * 480];
            float x1 = vc1[(size_t)m * 480];
            a0 += Lh0[m] * x0;
            a1 += Lh1[m] * x1;
        }
        if (i0 < 192) oc[i0] = a0; else og[i0 - 192] = a0;
        if (act1) og[i1 - 192] = a1;
    }

    // ---- o_pair = a @ z (z streamed; LLC-resident from k_zb for high n) ----
    {
        const int c = tid & 127, half = tid >> 7;
        float acc[HH];
        #pragma unroll
        for (int h = 0; h < HH; ++h) acc[h] = 0.f;
        const float* zr = z + (size_t)n * N_ * CZ + c;
        const int m0 = half * 384;
        #pragma unroll 2
        for (int m = m0; m < m0 + 384; ++m) {
            float zz = zr[(size_t)m * CZ];
            #pragma unroll
            for (int h = 0; h < HH; ++h) acc[h] += zz * L[h * N_ + m];
        }
        #pragma unroll
        for (int h = 0; h < HH; ++h) part[(half * HH + h) * CZ + c] = acc[h];
    }
    __syncthreads();

    // ---- inverse rotation + norms ----
    for (int hp = tid; hp < 96; hp += 256) {
        float gx = og[hp * 3 + 0] - T[0];
        float gy = og[hp * 3 + 1] - T[1];
        float gz = og[hp * 3 + 2] - T[2];
        float lx = R[0] * gx + R[3] * gy + R[6] * gz;
        float ly = R[1] * gx + R[4] * gy + R[7] * gz;
        float lz = R[2] * gx + R[5] * gy + R[8] * gz;
        oc[192 + hp] = lx;
        oc[288 + hp] = ly;
        oc[384 + hp] = lz;
        oc[480 + hp] = sqrtf(lx * lx + ly * ly + lz * lz + 1e-8f);
    }
    for (int i = tid; i < HH * CZ; i += 256)
        oc[576 + i] = part[i] + part[HH * CZ + i];
}

// ---------------------------------------------------------------------------
// K3: out[n][j] = o_cat[n,:] . w_out[j,:] + b_out[j]
// 2 residues per block: halves w_out L2 traffic, doubles FMA-chain ILP.
// ---------------------------------------------------------------------------
__global__ __launch_bounds__(384) void k_final(
    const float* __restrict__ ocat,
    const float* __restrict__ w_out,
    const float* __restrict__ b_out,
    float* __restrict__ out)
{
    const int n0 = blockIdx.x * 2, n1 = n0 + 1;
    const int tid = threadIdx.x;
    __shared__ float oc0[2112], oc1[2112];
    for (int i = tid; i < 2112; i += 384) {
        oc0[i] = ocat[(size_t)n0 * 2112 + i];
        oc1[i] = ocat[(size_t)n1 * 2112 + i];
    }
    __syncthreads();

    float acc0 = b_out[tid], acc1 = acc0;
    const float4* w4 = (const float4*)(w_out + (size_t)tid * 2112);
    #pragma unroll 4
    for (int c4 = 0; c4 < 2112 / 4; ++c4) {
        float4 wv = w4[c4];
        const float* s0 = &oc0[c4 * 4];
        const float* s1 = &oc1[c4 * 4];
        acc0 += s0[0] * wv.x + s0[1] * wv.y + s0[2] * wv.z + s0[3] * wv.w;
        acc1 += s1[0] * wv.x + s1[1] * wv.y + s1[2] * wv.z + s1[3] * wv.w;
    }
    out[n0 * 384 + tid] = acc0;
    out[n1 * 384 + tid] = acc1;
}

extern "C" void kernel_launch(void* const* d_in, const int* in_sizes, int n_in,
                              void* d_out, int out_size, void* d_ws, size_t ws_size,
                              hipStream_t stream)
{
    const float* s     = (const float*)d_in[0];
    const float* z     = (const float*)d_in[1];
    const float* rot   = (const float*)d_in[2];
    const float* trans = (const float*)d_in[3];
    const float* mask  = (const float*)d_in[4];
    const float* w_q   = (const float*)d_in[5];
    const float* b_q   = (const float*)d_in[6];
    const float* w_kv  = (const float*)d_in[7];
    const float* b_kv  = (const float*)d_in[8];
    const float* w_qp  = (const float*)d_in[9];
    const float* b_qp  = (const float*)d_in[10];
    const float* w_kvp = (const float*)d_in[11];
    const float* b_kvp = (const float*)d_in[12];
    const float* w_b   = (const float*)d_in[13];
    const float* b_b   = (const float*)d_in[14];
    const float* hwts  = (const float*)d_in[15];
    const float* w_out = (const float*)d_in[16];
    const float* b_out = (const float*)d_in[17];

    float* ws   = (float*)d_ws;
    float* q    = ws;                    // 768*192      =   147456
    float* k    = q    + 147456;         // 768*192      =   147456
    float* qp   = k    + 147456;         // 768*144      =   110592
    float* kp   = qp   + 110592;         // 768*144      =   110592
    float* vcat = kp   + 110592;         // 768*480      =   368640
    float* zb   = vcat + 368640;         // 768*768*12   =  7077888
    float* ocat = zb   + 7077888;        // 768*2112     =  1622016
    // total: 9,584,640 floats = 38.3 MB

    k_proj<<<N_, 256, 0, stream>>>(s, rot, trans, w_q, b_q, w_kv, b_kv,
                                   w_qp, b_qp, w_kvp, b_kvp, q, k, qp, kp, vcat);
    k_zb<<<N_ * 12, 256, 0, stream>>>(z, w_b, b_b, zb);
    k_fused<<<N_, 256, 0, stream>>>(q, k, qp, kp, vcat, zb, z,
                                    hwts, mask, rot, trans, ocat);
    k_final<<<N_ / 2, 384, 0, stream>>>(ocat, w_out, b_out, (float*)d_out);
}